// Round 11
// baseline (154.605 us; speedup 1.0000x reference)
//
#include <hip/hip_runtime.h>

#define BIG 1e8f
#define LN2 0.69314718f
#define QENC 1.7686573f   /* log2(e) * 255/208 : dist -> u8 code */
#define DDEC 0.81568627f  /* 208/255 : u8 code -> log2-units */

#define BROW 272          /* band row stride, bytes (256 cols + 16 pad) */

/* dynamic LDS layout */
#define OFF_XH    69632   /* band: [0, 69632) = 256 * 272 */
#define OFF_X2S   86016   /* xh: 16384 B f16 */
#define OFF_Y2S   87040
#define OFF_RDY   88064   /* 16 stripe flags */
#define LDS_BYTES 88128

typedef _Float16 half8 __attribute__((ext_vector_type(8)));
typedef float f32x4 __attribute__((ext_vector_type(4)));

__device__ __forceinline__ float exp2g(float x) {
#if __has_builtin(__builtin_amdgcn_exp2f)
    return __builtin_amdgcn_exp2f(x);
#else
    return exp2f(x);
#endif
}
__device__ __forceinline__ float log2g(float x) {
#if __has_builtin(__builtin_amdgcn_logf)
    return __builtin_amdgcn_logf(x);
#else
    return log2f(x);
#endif
}
// pair precompute: m = min(a,b), s = 2^(m-a)+2^(m-b) = 1 + 2^(-|a-b|)
__device__ __forceinline__ void pairp(float a, float b, float& m, float& s) {
    m = fminf(a, b);
    s = exp2g(-fabsf(a - b)) + 1.f;
}
// softmin of {pair (m,s), v}  (base-2 domain)
__device__ __forceinline__ float smp(float m, float s, float v) {
    float d = v - m;
    float t = exp2g(-fabsf(d));
    float r = (d > 0.f) ? (t + s) : fmaf(s, t, 1.f);
    return fminf(m, v) - log2g(r);
}
// wave shift-up-by-1 via DPP; lane 0 receives oldv.
__device__ __forceinline__ float shfl_up1(float v, float oldv) {
    int r = __builtin_amdgcn_update_dpp(
        __builtin_bit_cast(int, oldv), __builtin_bit_cast(int, v),
        0x138 /*wave_shr:1*/, 0xf, 0xf, false);
    return __builtin_bit_cast(float, r);
}
__device__ __forceinline__ int clampr(int r) {
    return r < 0 ? 0 : (r > 255 ? 255 : r);
}
__device__ __forceinline__ unsigned int pack_d(f32x4 acc, float xx, float4 yy) {
    float dv;
    unsigned int pk;
    dv = fminf(fmaxf(fmaf(-2.f, acc[0], xx + yy.x), 0.f) * QENC, 254.9f);
    pk = (unsigned int)(dv + 0.5f);
    dv = fminf(fmaxf(fmaf(-2.f, acc[1], xx + yy.y), 0.f) * QENC, 254.9f);
    pk |= (unsigned int)(dv + 0.5f) << 8;
    dv = fminf(fmaxf(fmaf(-2.f, acc[2], xx + yy.z), 0.f) * QENC, 254.9f);
    pk |= (unsigned int)(dv + 0.5f) << 16;
    dv = fminf(fmaxf(fmaf(-2.f, acc[3], xx + yy.w), 0.f) * QENC, 254.9f);
    pk |= (unsigned int)(dv + 0.5f) << 24;
    return pk;
}

// One block = one batch, 2 waves.
// Wave 1 (producer): MFMA distance matrix, u8 row-major, full 256x256 (no
//   ring). Forward-only stripe flags; NEVER waits -> sync DAG acyclic.
// Wave 0 (DP): lane t owns cols 4t+1..4t+4; superstep s processes the 4x4
//   tile rows 4(s-t)+1..+4 (127 supersteps). In-tile anti-diagonal ILP (~2.3)
//   hides softmin latency. Relay: 4 right-edge values e0..e3 + delayed diag
//   pe3 via DPP (lane 0 boundary injected through the DPP old operand).
__global__ __launch_bounds__(128, 1) void sdtw_kernel(
    const float* __restrict__ x, const float* __restrict__ y,
    float* __restrict__ out) {
    extern __shared__ __align__(16) char smem[];
    unsigned char* band = (unsigned char*)smem;
    _Float16* xh = (_Float16*)(smem + OFF_XH);
    float* x2s = (float*)(smem + OFF_X2S);
    float* y2s = (float*)(smem + OFF_Y2S);
    volatile int* rdyv = (volatile int*)(smem + OFF_RDY);

    const int tid = threadIdx.x;  // 0..127
    const int b = blockIdx.x;
    const float* xb = x + (size_t)b * 8192;
    const float* yb = y + (size_t)b * 8192;

    // ---- phase 0: stage x as f16 + norms (2 rows/thread); y norms ----
#pragma unroll
    for (int rr = 0; rr < 2; rr++) {
        const int r = tid + rr * 128;
        const float4* px = (const float4*)(xb + r * 32);
        union { _Float16 h[32]; half8 v[4]; } uc;
        float s2 = 0.f;
#pragma unroll
        for (int q = 0; q < 8; q++) {
            float4 f = px[q];
            s2 += f.x * f.x + f.y * f.y + f.z * f.z + f.w * f.w;
            uc.h[4 * q + 0] = (_Float16)f.x;
            uc.h[4 * q + 1] = (_Float16)f.y;
            uc.h[4 * q + 2] = (_Float16)f.z;
            uc.h[4 * q + 3] = (_Float16)f.w;
        }
        half8* dst = (half8*)&xh[r * 32];
#pragma unroll
        for (int q = 0; q < 4; q++) dst[q] = uc.v[q];
        x2s[r] = s2;

        const float4* py = (const float4*)(yb + r * 32);
        float t2 = 0.f;
#pragma unroll
        for (int q = 0; q < 8; q++) {
            float4 f = py[q];
            t2 += f.x * f.x + f.y * f.y + f.z * f.z + f.w * f.w;
        }
        y2s[r] = t2;
    }
    if (tid < 16) rdyv[tid] = 0;
    __syncthreads();

    if (tid >= 64) {
        // ================= producer wave (never waits) =================
        const int lane = tid - 64;
        const int qd = lane >> 4, xr = lane & 15;

        half8 yfrag[16];  // B-frags (static-indexed only -> stay in VGPRs)
#pragma unroll
        for (int ci = 0; ci < 16; ci++) {
            const float* yp = yb + (ci * 16 + xr) * 32 + qd * 8;
            float4 f0 = *(const float4*)yp;
            float4 f1 = *(const float4*)(yp + 4);
            half8 v;
            v[0] = (_Float16)f0.x; v[1] = (_Float16)f0.y;
            v[2] = (_Float16)f0.z; v[3] = (_Float16)f0.w;
            v[4] = (_Float16)f1.x; v[5] = (_Float16)f1.y;
            v[6] = (_Float16)f1.z; v[7] = (_Float16)f1.w;
            yfrag[ci] = v;
        }

        for (int sg = 0; sg < 16; sg++) {
            const half8 xf = *(const half8*)&xh[(sg * 16 + xr) * 32 + qd * 8];
            const float xx = x2s[sg * 16 + xr];
            unsigned char* rowp = &band[(sg * 16 + xr) * BROW];
#pragma unroll
            for (int ci = 0; ci < 16; ci++) {
                f32x4 acc = {0.f, 0.f, 0.f, 0.f};
                acc = __builtin_amdgcn_mfma_f32_16x16x32_f16(yfrag[ci], xf, acc, 0, 0, 0);
                const float4 yy = *(const float4*)&y2s[ci * 16 + qd * 4];
                // lane holds row 16sg+xr, cols ci*16+qd*4..+3 (R4-verified)
                *(unsigned int*)&rowp[ci * 16 + qd * 4] = pack_d(acc, xx, yy);
            }
            __threadfence_block();  // drain writes before flag
            if (lane == 0) rdyv[sg] = 1;
        }
        return;
    }

    // ================= DP wave =================
    const int t = tid;  // 0..63
    const int cofs = 4 * t;
    float u0 = BIG, u1 = BIG, u2 = BIG, u3 = BIG;      // D[i0-1][c0..c3]
    float e0 = BIG, e1 = BIG, e2 = BIG, e3 = BIG;      // D[i0..i0+3][c3]
    float pe3 = BIG;                                   // e3 one superstep ago

    while (rdyv[0] == 0) {}
    __threadfence_block();
    unsigned int w0, w1, w2, w3;
    {
        const int p = -t;  // s = 0
        w0 = *(const unsigned int*)&band[clampr(4 * p + 0) * BROW + cofs];
        w1 = *(const unsigned int*)&band[clampr(4 * p + 1) * BROW + cofs];
        w2 = *(const unsigned int*)&band[clampr(4 * p + 2) * BROW + cofs];
        w3 = *(const unsigned int*)&band[clampr(4 * p + 3) * BROW + cofs];
    }

    for (int s = 0; s < 127; s++) {
        if ((s & 3) == 0) {  // stripe gate: rows <= 4(s+4)+3 need stripe s/4+1
            int st = (s >> 2) + 1;
            if (st > 15) st = 15;
            while (rdyv[st] == 0) {}
            __threadfence_block();
        }

        // relay (values from superstep s-1 / s-2)
        const float L0 = shfl_up1(e0, BIG);
        const float L1 = shfl_up1(e1, BIG);
        const float L2 = shfl_up1(e2, BIG);
        const float L3 = shfl_up1(e3, BIG);
        const float G = shfl_up1(pe3, (s == 0) ? 0.f : BIG);
        pe3 = e3;

        // prefetch next superstep's 4 rows (off critical path)
        const int pn = s + 1 - t;
        const unsigned int nw0 = *(const unsigned int*)&band[clampr(4 * pn + 0) * BROW + cofs];
        const unsigned int nw1 = *(const unsigned int*)&band[clampr(4 * pn + 1) * BROW + cofs];
        const unsigned int nw2 = *(const unsigned int*)&band[clampr(4 * pn + 2) * BROW + cofs];
        const unsigned int nw3 = *(const unsigned int*)&band[clampr(4 * pn + 3) * BROW + cofs];

        // decode 16 distances (v_cvt_f32_ubyteN + mul)
        const float d00 = (float)(w0 & 255u) * DDEC;
        const float d01 = (float)((w0 >> 8) & 255u) * DDEC;
        const float d02 = (float)((w0 >> 16) & 255u) * DDEC;
        const float d03 = (float)(w0 >> 24) * DDEC;
        const float d10 = (float)(w1 & 255u) * DDEC;
        const float d11 = (float)((w1 >> 8) & 255u) * DDEC;
        const float d12 = (float)((w1 >> 16) & 255u) * DDEC;
        const float d13 = (float)(w1 >> 24) * DDEC;
        const float d20 = (float)(w2 & 255u) * DDEC;
        const float d21 = (float)((w2 >> 8) & 255u) * DDEC;
        const float d22 = (float)((w2 >> 16) & 255u) * DDEC;
        const float d23 = (float)(w2 >> 24) * DDEC;
        const float d30 = (float)(w3 & 255u) * DDEC;
        const float d31 = (float)((w3 >> 8) & 255u) * DDEC;
        const float d32 = (float)((w3 >> 16) & 255u) * DDEC;
        const float d33 = (float)(w3 >> 24) * DDEC;

        // 4x4 tile; v[k][j] = d + softmin(up, left, diag); pair = {up,diag}
        float m, sv;
        pairp(u0, G, m, sv);   const float v00 = d00 + smp(m, sv, L0);
        pairp(u1, u0, m, sv);  const float v01 = d01 + smp(m, sv, v00);
        pairp(u2, u1, m, sv);  const float v02 = d02 + smp(m, sv, v01);
        pairp(u3, u2, m, sv);  const float v03 = d03 + smp(m, sv, v02);

        pairp(v00, L0, m, sv); const float v10 = d10 + smp(m, sv, L1);
        pairp(v01, v00, m, sv); const float v11 = d11 + smp(m, sv, v10);
        pairp(v02, v01, m, sv); const float v12 = d12 + smp(m, sv, v11);
        pairp(v03, v02, m, sv); const float v13 = d13 + smp(m, sv, v12);

        pairp(v10, L1, m, sv); const float v20 = d20 + smp(m, sv, L2);
        pairp(v11, v10, m, sv); const float v21 = d21 + smp(m, sv, v20);
        pairp(v12, v11, m, sv); const float v22 = d22 + smp(m, sv, v21);
        pairp(v13, v12, m, sv); const float v23 = d23 + smp(m, sv, v22);

        pairp(v20, L2, m, sv); const float v30 = d30 + smp(m, sv, L3);
        pairp(v21, v20, m, sv); const float v31 = d31 + smp(m, sv, v30);
        pairp(v22, v21, m, sv); const float v32 = d32 + smp(m, sv, v31);
        pairp(v23, v22, m, sv); const float v33 = d33 + smp(m, sv, v32);

        const bool act = (unsigned)(s - t) < 64u;
        u0 = act ? v30 : u0;
        u1 = act ? v31 : u1;
        u2 = act ? v32 : u2;
        u3 = act ? v33 : u3;
        e0 = act ? v03 : e0;
        e1 = act ? v13 : e1;
        e2 = act ? v23 : e2;
        e3 = act ? v33 : e3;
        w0 = nw0; w1 = nw1; w2 = nw2; w3 = nw3;
    }

    if (t == 63) atomicAdd(out, u3 * (LN2 / 256.f));  // D[256][256] -> mean
}

extern "C" void kernel_launch(void* const* d_in, const int* in_sizes, int n_in,
                              void* d_out, int out_size, void* d_ws, size_t ws_size,
                              hipStream_t stream) {
    const float* x = (const float*)d_in[0];
    const float* y = (const float*)d_in[1];
    float* out = (float*)d_out;
    const int B = in_sizes[0] / (256 * 32);  // 256

    (void)hipFuncSetAttribute((const void*)sdtw_kernel,
                              hipFuncAttributeMaxDynamicSharedMemorySize,
                              LDS_BYTES);
    (void)hipMemsetAsync(d_out, 0, sizeof(float), stream);
    sdtw_kernel<<<dim3(B), dim3(128), LDS_BYTES, stream>>>(x, y, out);
}

// Round 12
// 141.557 us; speedup vs baseline: 1.0922x; 1.0922x over previous
//
#include <hip/hip_runtime.h>

#define BIG 1e8f
#define DEADS 1e9f          /* scale of a dead (infinite) value */
#define LN2 0.69314718f
#define LOG2E 1.44269504f
#define M2L -2.8853900818f  /* -2*log2(e) */

#define RSLOT 112           /* band ring slots (anti-diagonal rows) */
#define DRB 1040            /* drow stride bytes: 256 cols * 4B(half2) + 16 pad */

/* dynamic LDS layout (identical to R7's verified kernel) */
#define OFF_XH   116480     /* band: [0, 116480) = 112*1040 */
#define OFF_X2S  132864     /* xh: 16384 B f16 */
#define OFF_Y2S  133888
#define OFF_RDY  134912     /* 16 ready flags */
#define OFF_PRG  134976     /* consumer progress */
#define LDS_BYTES 135040

typedef _Float16 half8 __attribute__((ext_vector_type(8)));
typedef _Float16 half2_t __attribute__((ext_vector_type(2)));
typedef float f32x4 __attribute__((ext_vector_type(4)));

__device__ __forceinline__ float exp2g(float x) {
#if __has_builtin(__builtin_amdgcn_exp2f)
    return __builtin_amdgcn_exp2f(x);
#else
    return exp2f(x);
#endif
}
__device__ __forceinline__ float log2g(float x) {
#if __has_builtin(__builtin_amdgcn_logf)
    return __builtin_amdgcn_logf(x);
#else
    return log2f(x);
#endif
}
__device__ __forceinline__ half2_t pkrtz(float a, float b) {
    return __builtin_bit_cast(half2_t, __builtin_amdgcn_cvt_pkrtz(a, b));
}
// coefficient: 2^min(arg,0); clamp keeps dead-source args from producing inf
// (inf * P=0 would be NaN). For live sources arg <= 0 by anchor construction.
__device__ __forceinline__ float coef(float arg) {
    return exp2g(fminf(arg, 0.f));
}
// wave shift-up-by-1 via DPP; lane 0 receives oldv (boundary injection).
__device__ __forceinline__ float shfl_up1(float v, float oldv) {
    int r = __builtin_amdgcn_update_dpp(
        __builtin_bit_cast(int, oldv), __builtin_bit_cast(int, v),
        0x138 /*wave_shr:1*/, 0xf, 0xf, false);
    return __builtin_bit_cast(float, r);
}
__device__ __forceinline__ void dec2(unsigned int w, float& a, float& b) {
    half2_t h = __builtin_bit_cast(half2_t, w);
    a = (float)h[0];
    b = (float)h[1];
}

// One block = one batch, 2 waves on 2 SIMDs (R7 skeleton, new cell math).
// Wave 1 (producer): MFMA dist*log2(e) as f16 (dA,dB) pairs into the
//   anti-diagonal LDS ring. Identical to R7 (verified absmax 0).
// Wave 0 (DP): lane t owns cols 4t+1..4t+4; 2-row supersteps s=1..191.
//   NEW: scaled-linear softmin. Each value v = S - log2(P); anchors S chosen
//   off-chain as d + min(source anchors) so all coefficients are 2^(<=0)
//   (plain exp2f, flush = correct saturation) and P stays in [0,~32].
//   Serial chain = 8 f32 FMAs; all transcendentals off-chain.
__global__ __launch_bounds__(128, 1) void sdtw_kernel(
    const float* __restrict__ x, const float* __restrict__ y,
    float* __restrict__ out) {
    extern __shared__ __align__(16) char smem[];
    unsigned char* band = (unsigned char*)smem;
    _Float16* xh = (_Float16*)(smem + OFF_XH);
    float* x2sL = (float*)(smem + OFF_X2S);   // row norms * log2(e)
    float* y2sL = (float*)(smem + OFF_Y2S);
    volatile int* rdy = (volatile int*)(smem + OFF_RDY);
    volatile int* prg = (volatile int*)(smem + OFF_PRG);

    const int tid = threadIdx.x;  // 0..127
    const int b = blockIdx.x;
    const float* xb = x + (size_t)b * 8192;
    const float* yb = y + (size_t)b * 8192;

    // ---- phase 0 (both waves): stage x as f16 + scaled norms; flags ----
#pragma unroll
    for (int rr = 0; rr < 2; rr++) {
        const int r = tid + rr * 128;
        const float4* px = (const float4*)(xb + r * 32);
        union { _Float16 h[32]; half8 v[4]; } uc;
        float s2 = 0.f;
#pragma unroll
        for (int q = 0; q < 8; q++) {
            float4 f = px[q];
            s2 += f.x * f.x + f.y * f.y + f.z * f.z + f.w * f.w;
            uc.h[4 * q + 0] = (_Float16)f.x;
            uc.h[4 * q + 1] = (_Float16)f.y;
            uc.h[4 * q + 2] = (_Float16)f.z;
            uc.h[4 * q + 3] = (_Float16)f.w;
        }
        half8* dst = (half8*)&xh[r * 32];
#pragma unroll
        for (int q = 0; q < 4; q++) dst[q] = uc.v[q];
        x2sL[r] = s2 * LOG2E;

        const float4* py = (const float4*)(yb + r * 32);
        float t2 = 0.f;
#pragma unroll
        for (int q = 0; q < 8; q++) {
            float4 f = py[q];
            t2 += f.x * f.x + f.y * f.y + f.z * f.z + f.w * f.w;
        }
        y2sL[r] = t2 * LOG2E;
    }
    if (tid < 16) rdy[tid] = 0;
    if (tid == 16) *prg = 0;
    __syncthreads();

    if (tid >= 64) {
        // ================= producer wave (R7 verbatim) =================
        const int lane = tid - 64;
        const int qd = lane >> 4, xr = lane & 15;

        half8 yfrag[16];  // B-frags: lane holds y[ci*16+xr][qd*8+j]
        float yvL[16];
#pragma unroll
        for (int ci = 0; ci < 16; ci++) {
            const float* yp = yb + (ci * 16 + xr) * 32 + qd * 8;
            float4 f0 = *(const float4*)yp;
            float4 f1 = *(const float4*)(yp + 4);
            half8 v;
            v[0] = (_Float16)f0.x; v[1] = (_Float16)f0.y;
            v[2] = (_Float16)f0.z; v[3] = (_Float16)f0.w;
            v[4] = (_Float16)f1.x; v[5] = (_Float16)f1.y;
            v[6] = (_Float16)f1.z; v[7] = (_Float16)f1.w;
            yfrag[ci] = v;
            yvL[ci] = y2sL[ci * 16 + xr];
        }

        for (int sg = 0; sg < 16; sg++) {
            if (sg >= 6) {
                const int need = 8 * sg - 40;
                while (*prg < need) {}
            }
            const half8 xf = *(const half8*)&xh[(sg * 16 + xr) * 32 + qd * 8];
            const float4 xl = *(const float4*)&x2sL[sg * 16 + qd * 4];
            const int p0 = 8 * sg + 2 * qd;  // global pair of acc[0],acc[1]
#pragma unroll
            for (int ci = 0; ci < 16; ci++) {
                f32x4 acc = {0.f, 0.f, 0.f, 0.f};
                acc = __builtin_amdgcn_mfma_f32_16x16x32_f16(xf, yfrag[ci], acc, 0, 0, 0);
                const int c = ci * 16 + xr;
                const float yv = yvL[ci];
                const float d0 = fmaxf(fmaf(M2L, acc[0], xl.x + yv), 0.f);
                const float d1 = fmaxf(fmaf(M2L, acc[1], xl.y + yv), 0.f);
                const float d2 = fmaxf(fmaf(M2L, acc[2], xl.z + yv), 0.f);
                const float d3 = fmaxf(fmaf(M2L, acc[3], xl.w + yv), 0.f);
                const half2_t h01 = pkrtz(d0, d1);
                const half2_t h23 = pkrtz(d2, d3);
                const int dr0 = p0 + (c >> 2);          // anti-diagonal row
                int s0_ = dr0;     if (s0_ >= RSLOT) s0_ -= RSLOT;
                int s1_ = dr0 + 1; if (s1_ >= RSLOT) s1_ -= RSLOT;
                *(half2_t*)&band[s0_ * DRB + 4 * c] = h01;
                *(half2_t*)&band[s1_ * DRB + 4 * c] = h23;
            }
            __threadfence_block();
            if (lane == 0) rdy[sg] = 1;
        }
        return;
    }

    // ================= consumer (DP) wave =================
    const int lane = tid;
    // state: col j value = uS[j] - log2(uP[j]); dead = (P=0, S=DEADS)
    float uP0 = 0.f, uP1 = 0.f, uP2 = 0.f, uP3 = 0.f;
    float uS0 = DEADS, uS1 = DEADS, uS2 = DEADS, uS3 = DEADS;
    float pA3P = 0.f, pA3S = DEADS, pB3P = 0.f, pB3S = DEADS;
    float GP = (lane == 0) ? 1.f : 0.f;       // D[0][0] = 0 corner
    float GS = (lane == 0) ? 0.f : DEADS;

    while (rdy[0] == 0) {}
    uint4 wreg = *(const uint4*)&band[16 * lane];  // drow 0

    for (int s_ = 1; s_ <= 191; s_++) {
        // seam relay (lane 0 injected dead via DPP old operand)
        const float LP0 = shfl_up1(pA3P, 0.f);   // D[rA][c0-1] linear
        const float LS0 = shfl_up1(pA3S, DEADS);
        const float LP1 = shfl_up1(pB3P, 0.f);   // D[rB][c0-1]
        const float LS1 = shfl_up1(pB3S, DEADS);

        float dA0, dB0, dA1, dB1, dA2, dB2, dA3, dB3;
        dec2(wreg.x, dA0, dB0);
        dec2(wreg.y, dA1, dB1);
        dec2(wreg.z, dA2, dB2);
        dec2(wreg.w, dA3, dB3);

        // ring poll + progress publish (once per 8 supersteps)
        if ((s_ & 7) == 0) {
            int st = s_ >> 3;
            if (st > 15) st = 15;
            while (rdy[st] == 0) {}
            if (lane == 0) *prg = s_;
        }
        // prefetch next drow (used next superstep)
        int dn = (s_ > 190) ? 190 : s_;
        if (dn >= RSLOT) dn -= RSLOT;
        const uint4 wnext = *(const uint4*)&band[dn * DRB + 16 * lane];

        // ---- row A anchors: A_j = dA_j + min(up, diag, left anchors) ----
        const float A0 = dA0 + fminf(fminf(uS0, GS), LS0);
        const float A1 = dA1 + fminf(fminf(uS1, uS0), A0);
        const float A2 = dA2 + fminf(fminf(uS2, uS1), A1);
        const float A3 = dA3 + fminf(fminf(uS3, uS2), A2);
        const float k0 = A0 - dA0, k1 = A1 - dA1, k2 = A2 - dA2, k3 = A3 - dA3;

        // row A coefficients + off-chain partial sums
        const float bA0 = coef(k0 - uS0) * uP0 + coef(k0 - GS) * GP;
        const float bA1 = coef(k1 - uS1) * uP1 + coef(k1 - uS0) * uP0;
        const float bA2 = coef(k2 - uS2) * uP2 + coef(k2 - uS1) * uP1;
        const float bA3 = coef(k3 - uS3) * uP3 + coef(k3 - uS2) * uP2;
        const float cl0 = coef(k0 - LS0);
        const float cl1 = coef(k1 - A0);
        const float cl2 = coef(k2 - A1);
        const float cl3 = coef(k3 - A2);

        // row A chain: 4 FMAs
        const float PA0 = fmaf(cl0, LP0, bA0);
        const float PA1 = fmaf(cl1, PA0, bA1);
        const float PA2 = fmaf(cl2, PA1, bA2);
        const float PA3 = fmaf(cl3, PA2, bA3);

        // ---- row B anchors (up = row A, diag = row A shifted, left chain) --
        const float SB0 = dB0 + fminf(fminf(A0, LS0), LS1);
        const float SB1 = dB1 + fminf(fminf(A1, A0), SB0);
        const float SB2 = dB2 + fminf(fminf(A2, A1), SB1);
        const float SB3 = dB3 + fminf(fminf(A3, A2), SB2);
        const float q0 = SB0 - dB0, q1 = SB1 - dB1, q2 = SB2 - dB2, q3 = SB3 - dB3;

        const float bB0 = coef(q0 - A0) * PA0 + coef(q0 - LS0) * LP0;
        const float bB1 = coef(q1 - A1) * PA1 + coef(q1 - A0) * PA0;
        const float bB2 = coef(q2 - A2) * PA2 + coef(q2 - A1) * PA1;
        const float bB3 = coef(q3 - A3) * PA3 + coef(q3 - A2) * PA2;
        const float e0 = coef(q0 - LS1);
        const float e1 = coef(q1 - SB0);
        const float e2 = coef(q2 - SB1);
        const float e3 = coef(q3 - SB2);

        // row B chain: 4 FMAs
        const float PB0 = fmaf(e0, LP1, bB0);
        const float PB1 = fmaf(e1, PB0, bB1);
        const float PB2 = fmaf(e2, PB1, bB2);
        const float PB3 = fmaf(e3, PB2, bB3);

        // commit (lane active iff pair p = s_-lane-1 in [0,127])
        const bool act = (unsigned)(s_ - lane - 1) < 128u;
        uP0 = act ? PB0 : uP0;  uS0 = act ? SB0 : uS0;
        uP1 = act ? PB1 : uP1;  uS1 = act ? SB1 : uS1;
        uP2 = act ? PB2 : uP2;  uS2 = act ? SB2 : uS2;
        uP3 = act ? PB3 : uP3;  uS3 = act ? SB3 : uS3;
        pA3P = act ? PA3 : pA3P;  pA3S = act ? A3 : pA3S;
        pB3P = act ? PB3 : pB3P;  pB3S = act ? SB3 : pB3S;
        GP = LP1;  GS = LS1;   // diag(s+1) = D[rB(s)][c0-1], unconditional
        wreg = wnext;
    }

    if (lane == 63) {
        const float v = uS3 - log2g(uP3);         // back to log2 domain
        atomicAdd(out, v * (LN2 / 256.f));        // D[256][256] -> mean
    }
}

extern "C" void kernel_launch(void* const* d_in, const int* in_sizes, int n_in,
                              void* d_out, int out_size, void* d_ws, size_t ws_size,
                              hipStream_t stream) {
    const float* x = (const float*)d_in[0];
    const float* y = (const float*)d_in[1];
    float* out = (float*)d_out;
    const int B = in_sizes[0] / (256 * 32);  // 256

    (void)hipFuncSetAttribute((const void*)sdtw_kernel,
                              hipFuncAttributeMaxDynamicSharedMemorySize,
                              LDS_BYTES);
    (void)hipMemsetAsync(d_out, 0, sizeof(float), stream);
    sdtw_kernel<<<dim3(B), dim3(128), LDS_BYTES, stream>>>(x, y, out);
}